// Round 9
// baseline (330.759 us; speedup 1.0000x reference)
//
#include <hip/hip_runtime.h>
#include <cfloat>
#include <math.h>

// Problem constants
#define N_TEXT  226
#define N_IMG   5400
#define N_TOKEN 5626
#define N_HEAD  4

// Per-head block counts: 27, 36, 45, 54
// Block grid sizes: 27^2=729, 36^2=1296, 45^2=2025, 54^2=2916  (total 6966)
#define NB_QUANT_BLOCKS 6966
#define NCOPY 512
#define HEAD_STRIDE 31651876u   // N_TOKEN*N_TOKEN

// f32(1/15): XLA rewrites divide-by-constant into multiply-by-reciprocal.
#define RCP15 0x1.111112p-4f

// ---------------------------------------------------------------------------
// Quantize one bw x bw block, replicating XLA's canonicalized arithmetic:
//   scale = fl32(delta * fl32(1/15))            [div-by-const -> mul-by-rcp]
//   safe  = (scale==0) ? 1 : scale
//   t     = fl32(x * fl32(1/safe))              [div-by-broadcast -> mul-by-rcp]
//   q     = clip(roundeven(t), 0, 15)
//   out   = fl32(q * scale)
// The reciprocal-hoist (divide(X, broadcast(Y)) -> X * broadcast(1/Y)) is the
// ~1-ulp systematic deviation that all IEEE-division variants (r1-r8) missed.
// ---------------------------------------------------------------------------
template <int NB>
__device__ __forceinline__ void quant_block(const float* __restrict__ in,
                                            float* __restrict__ out,
                                            int local, int head) {
    constexpr int BW  = N_IMG / NB;   // 200 / 150 / 120 / 100
    constexpr int NV  = BW / 2;       // float2 per tile row
    constexpr int TOT = BW * NV;      // float2 per tile

    const int bi = local / NB;
    const int bj = local - bi * NB;

    const size_t base = (size_t)head * HEAD_STRIDE
                      + (size_t)(N_TEXT + bi * BW) * N_TOKEN
                      + (size_t)(N_TEXT + bj * BW);
    const float* ip = in + base;
    float*       op = out + base;

    const int tid = threadIdx.x;

    // ---- pass 1: block max (exact; order-independent) ----
    float m = -FLT_MAX;
    for (int i = tid; i < TOT; i += 256) {
        int r = i / NV;
        int c = i - r * NV;
        float2 v = *reinterpret_cast<const float2*>(ip + (size_t)r * N_TOKEN + 2 * c);
        m = fmaxf(m, fmaxf(v.x, v.y));
    }
    // wave-64 butterfly reduce
    #pragma unroll
    for (int off = 32; off > 0; off >>= 1)
        m = fmaxf(m, __shfl_xor(m, off));

    __shared__ float sm[4];
    if ((tid & 63) == 0) sm[tid >> 6] = m;
    __syncthreads();
    const float delta = fmaxf(fmaxf(sm[0], sm[1]), fmaxf(sm[2], sm[3]));

    // scale = delta * fl32(1/15)   (XLA const-divide rewrite)
    const float scale = __fmul_rn(delta, RCP15);
    const float safe  = (scale == 0.0f) ? 1.0f : scale;
    // hoisted correctly-rounded reciprocal of the broadcast divisor
    const float recip = __fdiv_rn(1.0f, safe);

    // ---- pass 2: fake-quant + store (re-read should hit L2/L3) ----
    for (int i = tid; i < TOT; i += 256) {
        int r = i / NV;
        int c = i - r * NV;
        const size_t off2 = (size_t)r * N_TOKEN + 2 * c;
        float2 v = *reinterpret_cast<const float2*>(ip + off2);
        // t = x * (1/safe): single-rounded reciprocal then multiply
        float qx = rintf(__fmul_rn(v.x, recip));
        float qy = rintf(__fmul_rn(v.y, recip));
        qx = fminf(fmaxf(qx, 0.0f), 15.0f);
        qy = fminf(fmaxf(qy, 0.0f), 15.0f);
        v.x = __fmul_rn(qx, scale);
        v.y = __fmul_rn(qy, scale);
        *reinterpret_cast<float2*>(op + off2) = v;
    }
}

// ---------------------------------------------------------------------------
// Copy the text regions (untouched by quantization):
//   Region A: rows [0,226) x all cols        -> contiguous per head, float4
//   Region B: rows [226,5626) x cols [0,226) -> float2 (113 per row)
// ---------------------------------------------------------------------------
__device__ __forceinline__ void copy_text(const float* __restrict__ in,
                                          float* __restrict__ out, int cb) {
    const int tid0   = cb * 256 + threadIdx.x;
    const int stride = NCOPY * 256;

    // Region A: 4 heads x 317869 float4 (= 226*5626 floats, 16B-aligned)
    for (int j = tid0; j < 4 * 317869; j += stride) {
        int head = j / 317869;
        int rem  = j - head * 317869;
        size_t addr = (size_t)head * HEAD_STRIDE + (size_t)rem * 4;
        *reinterpret_cast<float4*>(out + addr) =
            *reinterpret_cast<const float4*>(in + addr);
    }

    // Region B: 4 heads x 5400 rows x 113 float2
    for (int j = tid0; j < 4 * 610200; j += stride) {
        int head = j / 610200;
        int rem  = j - head * 610200;
        int row  = rem / 113;
        int col  = rem - row * 113;
        size_t addr = (size_t)head * HEAD_STRIDE
                    + (size_t)(N_TEXT + row) * N_TOKEN + 2 * col;
        *reinterpret_cast<float2*>(out + addr) =
            *reinterpret_cast<const float2*>(in + addr);
    }
}

// ---------------------------------------------------------------------------
__global__ __launch_bounds__(256)
void qam_kernel(const float* __restrict__ in, float* __restrict__ out) {
    const int b = blockIdx.x;
    if (b < 729) {
        quant_block<27>(in, out, b, 0);
    } else if (b < 2025) {
        quant_block<36>(in, out, b - 729, 1);
    } else if (b < 4050) {
        quant_block<45>(in, out, b - 2025, 2);
    } else if (b < NB_QUANT_BLOCKS) {
        quant_block<54>(in, out, b - 4050, 3);
    } else {
        copy_text(in, out, b - NB_QUANT_BLOCKS);
    }
}

extern "C" void kernel_launch(void* const* d_in, const int* in_sizes, int n_in,
                              void* d_out, int out_size, void* d_ws, size_t ws_size,
                              hipStream_t stream) {
    const float* x = (const float*)d_in[0];
    float* out     = (float*)d_out;
    const int grid = NB_QUANT_BLOCKS + NCOPY;
    qam_kernel<<<grid, 256, 0, stream>>>(x, out);
}